// Round 1
// baseline (373.289 us; speedup 1.0000x reference)
//
#include <hip/hip_runtime.h>
#include <math.h>

// Problem constants (from reference): B=64, S=4096, D=256
#define B_   64
#define S_   4096
#define D_   256
#define CH   32                         // chunks per batch (split-softmax partials)
#define ROWS_PER_CHUNK (S_ / CH)        // 128
#define WAVES_PER_BLOCK 4
#define ROWS_PER_WAVE (ROWS_PER_CHUNK / WAVES_PER_BLOCK)  // 32
#define LN_EPS 1e-3f

// Pass 1: one block per (batch, chunk). One wave per row: 64 lanes x float4 = D=256.
// Computes LN score online and accumulates online-softmax (m, l, acc[D]) per block.
__global__ __launch_bounds__(256) void pool_pass1(
    const float* __restrict__ x, const float* __restrict__ mask,
    const float* __restrict__ gamma, const float* __restrict__ w,
    float* __restrict__ ws_acc, float* __restrict__ ws_m, float* __restrict__ ws_l)
{
    const int blk   = blockIdx.x;
    const int b     = blk / CH;
    const int chunk = blk % CH;
    const int tid   = threadIdx.x;
    const int lane  = tid & 63;
    const int wave  = tid >> 6;
    const int d0    = lane * 4;

    // Per-lane gamma*w (beta and bias cancel in softmax — never loaded)
    const float4 g4 = *(const float4*)(gamma + d0);
    const float4 w4 = *(const float4*)(w + d0);
    float4 gw;
    gw.x = g4.x * w4.x; gw.y = g4.y * w4.y; gw.z = g4.z * w4.z; gw.w = g4.w * w4.w;
    float sgw = gw.x + gw.y + gw.z + gw.w;
    #pragma unroll
    for (int off = 32; off > 0; off >>= 1) sgw += __shfl_xor(sgw, off, 64);

    // Rows handled by this wave: chunk-local rows wave, wave+4, ... (consecutive
    // waves read consecutive rows each iteration -> 4 KiB contiguous per block iter)
    const int row0 = chunk * ROWS_PER_CHUNK + wave;
    const float* xrow = x + ((size_t)b * S_ + row0) * D_ + d0;
    const float* mrow = mask + (size_t)b * S_ + row0;

    float  m = -3.0e38f;
    float  l = 0.0f;
    float4 acc = make_float4(0.f, 0.f, 0.f, 0.f);

    // depth-1 prefetch to keep a 1 KiB load in flight during the shuffle chain
    float4 v   = *(const float4*)(xrow);
    float  msk = mrow[0];

    #pragma unroll 4
    for (int r = 0; r < ROWS_PER_WAVE; ++r) {
        const int rn = (r + 1 < ROWS_PER_WAVE) ? (r + 1) : r;
        float4 vnext = *(const float4*)(xrow + (size_t)rn * WAVES_PER_BLOCK * D_);
        float  mnext = mrow[rn * WAVES_PER_BLOCK];

        // three row reductions over the same data: sum, sumsq, dot(gw)
        float s1 = v.x + v.y + v.z + v.w;
        float s2 = v.x*v.x + v.y*v.y + v.z*v.z + v.w*v.w;
        float s3 = v.x*gw.x + v.y*gw.y + v.z*gw.z + v.w*gw.w;
        #pragma unroll
        for (int off = 32; off > 0; off >>= 1) {
            s1 += __shfl_xor(s1, off, 64);
            s2 += __shfl_xor(s2, off, 64);
            s3 += __shfl_xor(s3, off, 64);
        }
        const float mu    = s1 * (1.0f / D_);
        const float var   = s2 * (1.0f / D_) - mu * mu;
        const float rstd  = rsqrtf(var + LN_EPS);
        const float score = rstd * (s3 - mu * sgw) + (1.0f - msk) * -1e9f;

        // online softmax update
        const float mn    = fmaxf(m, score);
        const float scale = __expf(m - mn);
        const float p     = __expf(score - mn);
        m = mn;
        l = l * scale + p;
        acc.x = acc.x * scale + p * v.x;
        acc.y = acc.y * scale + p * v.y;
        acc.z = acc.z * scale + p * v.z;
        acc.w = acc.w * scale + p * v.w;

        v = vnext; msk = mnext;
    }

    // combine the 4 waves' partials in LDS
    __shared__ float s_acc[WAVES_PER_BLOCK][D_];
    __shared__ float s_m[WAVES_PER_BLOCK];
    __shared__ float s_l[WAVES_PER_BLOCK];
    *(float4*)&s_acc[wave][d0] = acc;
    if (lane == 0) { s_m[wave] = m; s_l[wave] = l; }
    __syncthreads();

    const float M  = fmaxf(fmaxf(s_m[0], s_m[1]), fmaxf(s_m[2], s_m[3]));
    const float e0 = __expf(s_m[0] - M), e1 = __expf(s_m[1] - M);
    const float e2 = __expf(s_m[2] - M), e3 = __expf(s_m[3] - M);
    const float L  = e0 * s_l[0] + e1 * s_l[1] + e2 * s_l[2] + e3 * s_l[3];
    const float a  = e0 * s_acc[0][tid] + e1 * s_acc[1][tid]
                   + e2 * s_acc[2][tid] + e3 * s_acc[3][tid];

    ws_acc[(size_t)blk * D_ + tid] = a;
    if (tid == 0) { ws_m[blk] = M; ws_l[blk] = L; }
}

// Pass 2: merge the CH partials per batch. One block per batch, one thread per d.
__global__ __launch_bounds__(256) void pool_pass2(
    const float* __restrict__ ws_acc, const float* __restrict__ ws_m,
    const float* __restrict__ ws_l, float* __restrict__ out)
{
    const int b = blockIdx.x;
    const int d = threadIdx.x;

    float M = -3.0e38f;
    #pragma unroll
    for (int c = 0; c < CH; ++c) M = fmaxf(M, ws_m[b * CH + c]);

    float L = 0.0f, a = 0.0f;
    #pragma unroll
    for (int c = 0; c < CH; ++c) {
        const float e = __expf(ws_m[b * CH + c] - M);
        L += e * ws_l[b * CH + c];
        a += e * ws_acc[((size_t)(b * CH + c)) * D_ + d];
    }
    out[(size_t)b * D_ + d] = a / L;
}

extern "C" void kernel_launch(void* const* d_in, const int* in_sizes, int n_in,
                              void* d_out, int out_size, void* d_ws, size_t ws_size,
                              hipStream_t stream) {
    // setup_inputs order: x, mask, gamma, beta, w, b
    const float* x     = (const float*)d_in[0];
    const float* mask  = (const float*)d_in[1];
    const float* gamma = (const float*)d_in[2];
    // d_in[3] = beta : cancels in softmax, unused
    const float* w     = (const float*)d_in[4];
    // d_in[5] = b    : cancels in softmax, unused
    float* out = (float*)d_out;

    // workspace layout: acc[B*CH*D] | m[B*CH] | l[B*CH]  (~2.02 MB)
    float* ws_acc = (float*)d_ws;
    float* ws_m   = ws_acc + (size_t)B_ * CH * D_;
    float* ws_l   = ws_m + B_ * CH;

    pool_pass1<<<B_ * CH, 256, 0, stream>>>(x, mask, gamma, w, ws_acc, ws_m, ws_l);
    pool_pass2<<<B_, 256, 0, stream>>>(ws_acc, ws_m, ws_l, out);
}

// Round 2
// 363.038 us; speedup vs baseline: 1.0282x; 1.0282x over previous
//
#include <hip/hip_runtime.h>
#include <math.h>

// Problem constants (from reference): B=64, S=4096, D=256
#define B_   64
#define S_   4096
#define D_   256
#define CH   32                          // chunks per batch (split-softmax partials)
#define ROWS_PER_CHUNK (S_ / CH)         // 128
#define NWAVE 4
#define ROWS_PER_BLOCK_ITER (NWAVE * 4)  // 16 (4 rows per wave, one per 16-lane quarter)
#define NITER (ROWS_PER_CHUNK / ROWS_PER_BLOCK_ITER)  // 8
#define LN_EPS 1e-3f

// Pass 1: one block per (batch, chunk). 16 lanes per row, 4 rows per wave.
// Lane (q = lane>>4, t = lane&15) owns row r+q, features d = t*4 + 64*k (k=0..3)
// -> each float4 load instr = 4 rows x 256 B contiguous segments (ideal coalescing),
// and the score reduction needs only a 4-round butterfly (offsets 8,4,2,1),
// i.e. 3 ds_swizzle per row instead of 18 (R1's LDS-pipe bottleneck).
__global__ __launch_bounds__(256) void pool_pass1(
    const float* __restrict__ x, const float* __restrict__ mask,
    const float* __restrict__ gamma, const float* __restrict__ w,
    float* __restrict__ ws_acc, float* __restrict__ ws_m, float* __restrict__ ws_l)
{
    const int blk   = blockIdx.x;
    const int b     = blk / CH;
    const int chunk = blk % CH;
    const int tid   = threadIdx.x;
    const int lane  = tid & 63;
    const int wave  = tid >> 6;
    const int q     = lane >> 4;   // quarter: which of 4 rows this lane works on
    const int t     = lane & 15;   // sublane within the row's 16-lane team

    // gamma*w for this lane's 16 features (beta & bias cancel in softmax)
    float4 gw[4];
    float sgw = 0.0f;
    #pragma unroll
    for (int k = 0; k < 4; ++k) {
        const int d = t * 4 + 64 * k;
        const float4 g4 = *(const float4*)(gamma + d);
        const float4 w4 = *(const float4*)(w + d);
        gw[k].x = g4.x * w4.x; gw[k].y = g4.y * w4.y;
        gw[k].z = g4.z * w4.z; gw[k].w = g4.w * w4.w;
        sgw += gw[k].x + gw[k].y + gw[k].z + gw[k].w;
    }
    #pragma unroll
    for (int off = 8; off > 0; off >>= 1) sgw += __shfl_xor(sgw, off, 64);

    // this lane's row at iteration i: chunk*128 + i*16 + wave*4 + q
    const int row0 = chunk * ROWS_PER_CHUNK + wave * 4 + q;
    const float* xbase = x + ((size_t)b * S_ + row0) * D_ + t * 4;
    const float* mbase = mask + (size_t)b * S_ + row0;

    float  m = -3.0e38f;
    float  l = 0.0f;
    float4 acc[4];
    #pragma unroll
    for (int k = 0; k < 4; ++k) acc[k] = make_float4(0.f, 0.f, 0.f, 0.f);

    // depth-1 prefetch: 4 KiB of row data in flight across the reduce/softmax
    float4 v[4];
    #pragma unroll
    for (int k = 0; k < 4; ++k) v[k] = *(const float4*)(xbase + 64 * k);
    float msk = mbase[0];

    for (int i = 0; i < NITER; ++i) {
        const int inx = (i + 1 < NITER) ? i + 1 : i;
        float4 vn[4];
        #pragma unroll
        for (int k = 0; k < 4; ++k)
            vn[k] = *(const float4*)(xbase + (size_t)inx * ROWS_PER_BLOCK_ITER * D_ + 64 * k);
        const float mskn = mbase[inx * ROWS_PER_BLOCK_ITER];

        // three row reductions over the same data: sum, sumsq, dot(gamma*w)
        float s1 = 0.f, s2 = 0.f, s3 = 0.f;
        #pragma unroll
        for (int k = 0; k < 4; ++k) {
            s1 += v[k].x + v[k].y + v[k].z + v[k].w;
            s2 += v[k].x*v[k].x + v[k].y*v[k].y + v[k].z*v[k].z + v[k].w*v[k].w;
            s3 += v[k].x*gw[k].x + v[k].y*gw[k].y + v[k].z*gw[k].z + v[k].w*gw[k].w;
        }
        #pragma unroll
        for (int off = 8; off > 0; off >>= 1) {
            s1 += __shfl_xor(s1, off, 64);
            s2 += __shfl_xor(s2, off, 64);
            s3 += __shfl_xor(s3, off, 64);
        }
        const float mu    = s1 * (1.0f / D_);
        const float var   = s2 * (1.0f / D_) - mu * mu;
        const float rstd  = rsqrtf(var + LN_EPS);
        const float score = rstd * (s3 - mu * sgw) + (1.0f - msk) * -1e9f;

        // online softmax update (per 16-lane quarter; identical within quarter)
        const float mnew  = fmaxf(m, score);
        const float scale = __expf(m - mnew);
        const float p     = __expf(score - mnew);
        m = mnew;
        l = l * scale + p;
        #pragma unroll
        for (int k = 0; k < 4; ++k) {
            acc[k].x = acc[k].x * scale + p * v[k].x;
            acc[k].y = acc[k].y * scale + p * v[k].y;
            acc[k].z = acc[k].z * scale + p * v[k].z;
            acc[k].w = acc[k].w * scale + p * v[k].w;
        }

        #pragma unroll
        for (int k = 0; k < 4; ++k) v[k] = vn[k];
        msk = mskn;
    }

    // combine the 16 row-groups' partials in LDS
    __shared__ float s_acc[NWAVE * 4][D_];
    __shared__ float s_m[NWAVE * 4];
    __shared__ float s_l[NWAVE * 4];
    const int g = wave * 4 + q;
    #pragma unroll
    for (int k = 0; k < 4; ++k) *(float4*)&s_acc[g][t * 4 + 64 * k] = acc[k];
    if (t == 0) { s_m[g] = m; s_l[g] = l; }
    __syncthreads();

    float M = -3.0e38f;
    #pragma unroll
    for (int gg = 0; gg < 16; ++gg) M = fmaxf(M, s_m[gg]);
    float L = 0.f, a = 0.f;
    #pragma unroll
    for (int gg = 0; gg < 16; ++gg) {
        const float e = __expf(s_m[gg] - M);
        L += e * s_l[gg];
        a += e * s_acc[gg][tid];
    }
    ws_acc[(size_t)blk * D_ + tid] = a;
    if (tid == 0) { ws_m[blk] = M; ws_l[blk] = L; }
}

// Pass 2: merge the CH partials per batch. One block per batch, one thread per d.
__global__ __launch_bounds__(256) void pool_pass2(
    const float* __restrict__ ws_acc, const float* __restrict__ ws_m,
    const float* __restrict__ ws_l, float* __restrict__ out)
{
    const int b = blockIdx.x;
    const int d = threadIdx.x;

    float M = -3.0e38f;
    #pragma unroll
    for (int c = 0; c < CH; ++c) M = fmaxf(M, ws_m[b * CH + c]);

    float L = 0.0f, a = 0.0f;
    #pragma unroll
    for (int c = 0; c < CH; ++c) {
        const float e = __expf(ws_m[b * CH + c] - M);
        L += e * ws_l[b * CH + c];
        a += e * ws_acc[((size_t)(b * CH + c)) * D_ + d];
    }
    out[(size_t)b * D_ + d] = a / L;
}

extern "C" void kernel_launch(void* const* d_in, const int* in_sizes, int n_in,
                              void* d_out, int out_size, void* d_ws, size_t ws_size,
                              hipStream_t stream) {
    // setup_inputs order: x, mask, gamma, beta, w, b
    const float* x     = (const float*)d_in[0];
    const float* mask  = (const float*)d_in[1];
    const float* gamma = (const float*)d_in[2];
    // d_in[3] = beta : cancels in softmax, unused
    const float* w     = (const float*)d_in[4];
    // d_in[5] = b    : cancels in softmax, unused
    float* out = (float*)d_out;

    // workspace layout: acc[B*CH*D] | m[B*CH] | l[B*CH]  (~2.02 MB)
    float* ws_acc = (float*)d_ws;
    float* ws_m   = ws_acc + (size_t)B_ * CH * D_;
    float* ws_l   = ws_m + B_ * CH;

    pool_pass1<<<B_ * CH, 256, 0, stream>>>(x, mask, gamma, w, ws_acc, ws_m, ws_l);
    pool_pass2<<<B_, 256, 0, stream>>>(ws_acc, ws_m, ws_l, out);
}